// Round 1
// baseline (2447.778 us; speedup 1.0000x reference)
//
#include <hip/hip_runtime.h>
#include <cmath>

typedef unsigned long long u64;
typedef unsigned int u32;
typedef unsigned char u8;

#define SCAN_BLOCK 256
#define SCAN_ELEMS 8
#define SCAN_TILE (SCAN_BLOCK * SCAN_ELEMS)

__constant__ int d_NUMTRI[16] = {0,1,1,2,1,2,2,1,1,2,2,1,2,1,1,0};
__constant__ int d_TRI[16][6] = {
 {-1,-1,-1,-1,-1,-1},{1,0,2,-1,-1,-1},{4,0,3,-1,-1,-1},{1,4,2,1,3,4},
 {3,1,5,-1,-1,-1},{2,3,0,2,5,3},{1,4,0,1,5,4},{4,2,5,-1,-1,-1},
 {4,5,2,-1,-1,-1},{4,1,0,4,5,1},{3,2,0,3,5,2},{1,3,5,-1,-1,-1},
 {4,1,2,4,3,1},{3,0,4,-1,-1,-1},{2,0,1,-1,-1,-1},{-1,-1,-1,-1,-1,-1}};
__constant__ int d_E0[6] = {0,0,0,1,1,2};
__constant__ int d_E1[6] = {1,2,3,2,3,3};

// ---------------- scans (exclusive, u64) ----------------
__global__ void scanA(const u64* in, u64* out, int n, u64* blockSums) {
    __shared__ u64 tsum[SCAN_BLOCK];
    int tbase = blockIdx.x * SCAN_TILE + threadIdx.x * SCAN_ELEMS;
    u64 vals[SCAN_ELEMS];
    u64 run = 0;
    for (int k = 0; k < SCAN_ELEMS; ++k) {
        int i = tbase + k;
        u64 v = (i < n) ? in[i] : 0ull;
        vals[k] = run;
        run += v;
    }
    tsum[threadIdx.x] = run;
    __syncthreads();
    for (int off = 1; off < SCAN_BLOCK; off <<= 1) {
        u64 v = (threadIdx.x >= (unsigned)off) ? tsum[threadIdx.x - off] : 0ull;
        __syncthreads();
        tsum[threadIdx.x] += v;
        __syncthreads();
    }
    u64 texcl = (threadIdx.x == 0) ? 0ull : tsum[threadIdx.x - 1];
    for (int k = 0; k < SCAN_ELEMS; ++k) {
        int i = tbase + k;
        if (i < n) out[i] = texcl + vals[k];
    }
    if (threadIdx.x == SCAN_BLOCK - 1) blockSums[blockIdx.x] = tsum[SCAN_BLOCK - 1];
}

__global__ void scanB(u64* bs, int nb, u64* totalOut) {
    __shared__ u64 sh[2048];
    for (int i = threadIdx.x; i < 2048; i += 256) sh[i] = (i < nb) ? bs[i] : 0ull;
    __syncthreads();
    for (int off = 1; off < 2048; off <<= 1) {
        u64 v[8];
        for (int k = 0; k < 8; ++k) {
            int i = threadIdx.x + k * 256;
            v[k] = (i >= off) ? sh[i - off] : 0ull;
        }
        __syncthreads();
        for (int k = 0; k < 8; ++k) sh[threadIdx.x + k * 256] += v[k];
        __syncthreads();
    }
    for (int i = threadIdx.x; i < nb; i += 256) bs[i] = (i == 0) ? 0ull : sh[i - 1];
    if (threadIdx.x == 0 && totalOut) *totalOut = (nb > 0) ? sh[nb - 1] : 0ull;
}

__global__ void scanC(u64* out, int n, const u64* bs) {
    int base = blockIdx.x * SCAN_TILE;
    u64 add = bs[blockIdx.x];
    int end = base + SCAN_TILE; if (end > n) end = n;
    for (int i = base + threadIdx.x; i < end; i += SCAN_BLOCK) out[i] += add;
}

// ---------------- pipeline kernels ----------------
__global__ void k_occ(const float* sdf, u32* occ, int V) {
    int i = blockIdx.x * 256 + threadIdx.x;
    if (i < V) occ[i] = (sdf[i] > 0.0f) ? 1u : 0u;
}

__global__ void k_classify(const int* tet, const u32* occ, u8* ti8, u64* tetPacked, int T) {
    int t = blockIdx.x * 256 + threadIdx.x;
    if (t >= T) return;
    int4 q = reinterpret_cast<const int4*>(tet)[t];
    int ti = (int)occ[q.x] | ((int)occ[q.y] << 1) | ((int)occ[q.z] << 2) | ((int)occ[q.w] << 3);
    ti8[t] = (u8)ti;
    int nt = d_NUMTRI[ti];
    tetPacked[t] = ((u64)(nt == 1 ? 1 : 0) << 21) | (u64)(nt == 2 ? 1 : 0);
}

__global__ void k_count(const int* tet, const u8* ti8, u64* bucketCnt, int T) {
    int t = blockIdx.x * 256 + threadIdx.x;
    if (t >= T) return;
    int ti = ti8[t];
    if (d_NUMTRI[ti] == 0) return;
    int4 q = reinterpret_cast<const int4*>(tet)[t];
    int idx[4] = {q.x, q.y, q.z, q.w};
    for (int e = 0; e < 6; ++e) {
        int a = idx[d_E0[e]], b = idx[d_E1[e]];
        int mn = a < b ? a : b;
        atomicAdd(&bucketCnt[mn], 1ull);
    }
}

__global__ void k_fill(const int* tet, const u8* ti8, const u64* bucketStart, u32* cursor,
                       int* maxArr, int T) {
    int t = blockIdx.x * 256 + threadIdx.x;
    if (t >= T) return;
    int ti = ti8[t];
    if (d_NUMTRI[ti] == 0) return;
    int4 q = reinterpret_cast<const int4*>(tet)[t];
    int idx[4] = {q.x, q.y, q.z, q.w};
    for (int e = 0; e < 6; ++e) {
        int a = idx[d_E0[e]], b = idx[d_E1[e]];
        int mn = a < b ? a : b;
        int mx = a < b ? b : a;
        u32 slot = atomicAdd(&cursor[mn], 1u);
        maxArr[(long long)bucketStart[mn] + slot] = mx;
    }
}

__global__ void k_sortdedup(const u64* bucketStart, const u64* bucketCnt, int* maxArr,
                            const u32* occ, u64* packedUC, int V) {
    int v = blockIdx.x * 256 + threadIdx.x;
    if (v >= V) return;
    int start = (int)bucketStart[v];
    int n = (int)bucketCnt[v];
    int* arr = maxArr + start;
    // insertion sort (buckets ~26 elems avg; L1/L2 resident)
    for (int i = 1; i < n; ++i) {
        int key = arr[i];
        int j = i - 1;
        while (j >= 0 && arr[j] > key) { arr[j + 1] = arr[j]; --j; }
        arr[j + 1] = key;
    }
    // dedup in place + count unique / crossing
    int u = 0, c = 0, prev = -1;
    u32 ov = occ[v];
    for (int i = 0; i < n; ++i) {
        int b = arr[i];
        if (b != prev) {
            arr[u++] = b;
            prev = b;
            c += (int)(ov ^ occ[b]);
        }
    }
    packedUC[v] = ((u64)u << 23) | (u64)c;
}

__global__ void k_verts_map(const u64* bucketStart, const u64* packedUC, const u64* ucScan,
                            const int* maxArr, int* mapArr, const u32* occ,
                            const float* pos, const float* sdf, float* out, int V) {
    int v = blockIdx.x * 256 + threadIdx.x;
    if (v >= V) return;
    int start = (int)bucketStart[v];
    int u = (int)(packedUC[v] >> 23);
    int cBase = (int)(ucScan[v] & 0x7fffffull);
    u32 ov = occ[v];
    float s0 = sdf[v];
    float p0x = pos[3 * v], p0y = pos[3 * v + 1], p0z = pos[3 * v + 2];
    int c = 0;
    for (int j = 0; j < u; ++j) {
        int b = maxArr[start + j];
        if (ov ^ occ[b]) {
            int k = cBase + (c++);
            mapArr[start + j] = k;
            float s1 = sdf[b];
            float d = s0 - s1;
            float w0 = -s1 / d, w1 = s0 / d;
            out[3LL * k + 0] = p0x * w0 + pos[3 * b + 0] * w1;
            out[3LL * k + 1] = p0y * w0 + pos[3 * b + 1] * w1;
            out[3LL * k + 2] = p0z * w0 + pos[3 * b + 2] * w1;
        } else {
            mapArr[start + j] = -1;
        }
    }
}

__global__ void k_faces(const int* tet, const u8* ti8, const u64* tetScan,
                        const u64* bucketStart, const u64* packedUC,
                        const int* maxArr, const int* mapArr, const u64* meta,
                        float* out, int T, int Ngrid, long long uvFloats) {
    int t = blockIdx.x * 256 + threadIdx.x;
    if (t >= T) return;
    int ti = ti8[t];
    int nt = d_NUMTRI[ti];
    if (nt == 0) return;

    u64 tot = meta[0];
    int C1 = (int)((tot >> 21) & 0x1fffffull);
    int C2 = (int)(tot & 0x1fffffull);
    int Ne = (int)(meta[2] & 0x7fffffull);
    long long facesBase = 3LL * Ne;
    long long F = (long long)C1 + 2LL * C2;
    long long uvIdxBase = facesBase + 3LL * F + uvFloats;

    int4 q = reinterpret_cast<const int4*>(tet)[t];
    int idx[4] = {q.x, q.y, q.z, q.w};
    int emap[6];
    for (int e = 0; e < 6; ++e) {
        int a = idx[d_E0[e]], b = idx[d_E1[e]];
        if (a > b) { int tmp = a; a = b; b = tmp; }
        int start = (int)bucketStart[a];
        int u = (int)(packedUC[a] >> 23);
        int lo = 0, hi = u;
        while (lo < hi) {
            int mid = (lo + hi) >> 1;
            if (maxArr[start + mid] < b) lo = mid + 1; else hi = mid;
        }
        emap[e] = mapArr[start + lo];
    }

    u64 sc = tetScan[t];
    int r1 = (int)((sc >> 21) & 0x1fffffull);
    int r2 = (int)(sc & 0x1fffffull);
    int tet_idx = (t / Ngrid) * Ngrid + (t % Ngrid);
    const int* row = d_TRI[ti];

    if (nt == 1) {
        long long f = r1;
        out[facesBase + 3 * f + 0] = (float)emap[row[0]];
        out[facesBase + 3 * f + 1] = (float)emap[row[1]];
        out[facesBase + 3 * f + 2] = (float)emap[row[2]];
        // tri_idx = 0
        out[uvIdxBase + 3 * f + 0] = (float)(4 * tet_idx);
        out[uvIdxBase + 3 * f + 1] = (float)(4 * tet_idx + 1);
        out[uvIdxBase + 3 * f + 2] = (float)(4 * tet_idx + 2);
    } else {
        long long f0 = (long long)C1 + 2LL * r2;
        out[facesBase + 3 * f0 + 0] = (float)emap[row[0]];
        out[facesBase + 3 * f0 + 1] = (float)emap[row[1]];
        out[facesBase + 3 * f0 + 2] = (float)emap[row[2]];
        out[facesBase + 3 * (f0 + 1) + 0] = (float)emap[row[3]];
        out[facesBase + 3 * (f0 + 1) + 1] = (float)emap[row[4]];
        out[facesBase + 3 * (f0 + 1) + 2] = (float)emap[row[5]];
        // row f0: tri_idx = 0 ; row f0+1: tri_idx = 1
        out[uvIdxBase + 3 * f0 + 0] = (float)(4 * tet_idx);
        out[uvIdxBase + 3 * f0 + 1] = (float)(4 * tet_idx + 1);
        out[uvIdxBase + 3 * f0 + 2] = (float)(4 * tet_idx + 2);
        out[uvIdxBase + 3 * (f0 + 1) + 0] = (float)(4 * tet_idx);
        out[uvIdxBase + 3 * (f0 + 1) + 1] = (float)(4 * tet_idx + 2);
        out[uvIdxBase + 3 * (f0 + 1) + 2] = (float)(4 * tet_idx + 3);
    }
}

__global__ void k_uvs(float* out, const u64* meta, int Ngrid) {
    int c = blockIdx.x * 256 + threadIdx.x;
    int total = Ngrid * Ngrid;
    if (c >= total) return;
    u64 tot = meta[0];
    int C1 = (int)((tot >> 21) & 0x1fffffull);
    int C2 = (int)(tot & 0x1fffffull);
    int Ne = (int)(meta[2] & 0x7fffffull);
    long long uvBase = 3LL * Ne + 3LL * ((long long)C1 + 2LL * C2);
    int i = c / Ngrid, j = c % Ngrid;
    double step = (Ngrid > 1) ? (1.0 - 1.0 / (double)Ngrid) / (double)(Ngrid - 1) : 0.0;
    float x = (float)((double)j * step);
    float y = (float)((double)i * step);
    float pad = (float)(0.9 / (double)Ngrid);
    long long o = uvBase + 8LL * c;
    out[o + 0] = x;       out[o + 1] = y;
    out[o + 2] = x + pad; out[o + 3] = y;
    out[o + 4] = x + pad; out[o + 5] = y + pad;
    out[o + 6] = x;       out[o + 7] = y + pad;
}

// ---------------- host ----------------
static void run_scan(const u64* in, u64* out, int n, u64* blockSums, u64* totalOut,
                     hipStream_t stream) {
    int nb = (n + SCAN_TILE - 1) / SCAN_TILE;
    scanA<<<nb, SCAN_BLOCK, 0, stream>>>(in, out, n, blockSums);
    scanB<<<1, 256, 0, stream>>>(blockSums, nb, totalOut);
    scanC<<<nb, SCAN_BLOCK, 0, stream>>>(out, n, blockSums);
}

extern "C" void kernel_launch(void* const* d_in, const int* in_sizes, int n_in,
                              void* d_out, int out_size, void* d_ws, size_t ws_size,
                              hipStream_t stream) {
    const float* pos = (const float*)d_in[0];
    const float* sdf = (const float*)d_in[1];
    const int* tet = (const int*)d_in[2];
    int V = in_sizes[1];
    int T = in_sizes[2] / 4;
    float* out = (float*)d_out;

    // workspace carve-up (all regions either memset here or fully written before read)
    char* p = (char*)d_ws;
    auto alloc = [&](size_t bytes) -> void* {
        void* r = (void*)p;
        p += (bytes + 255) & ~(size_t)255;
        return r;
    };
    u32* occ        = (u32*)alloc((size_t)V * 4);
    u8*  ti8        = (u8*) alloc((size_t)T);
    u64* tetPacked  = (u64*)alloc((size_t)T * 8);
    u64* tetScan    = (u64*)alloc((size_t)T * 8);
    u64* bucketCnt  = (u64*)alloc((size_t)V * 8);
    u64* bucketStart= (u64*)alloc((size_t)V * 8);
    u32* cursor     = (u32*)alloc((size_t)V * 4);
    u64* packedUC   = (u64*)alloc((size_t)V * 8);
    u64* ucScan     = (u64*)alloc((size_t)V * 8);
    int* maxArr     = (int*)alloc((size_t)6 * T * 4);
    int* mapArr     = (int*)alloc((size_t)6 * T * 4);
    u64* blockSums  = (u64*)alloc(2048 * 8);
    u64* meta       = (u64*)alloc(16 * 8);

    // Ngrid = ceil(sqrt((2T+1)//2)) = ceil(sqrt(T))
    long long M = (2LL * T + 1) / 2;
    int Ngrid = (int)std::sqrt((double)M);
    while ((long long)Ngrid * Ngrid < M) ++Ngrid;
    if (Ngrid < 1) Ngrid = 1;
    long long uvFloats = 8LL * Ngrid * Ngrid;

    hipMemsetAsync(bucketCnt, 0, (size_t)V * 8, stream);
    hipMemsetAsync(cursor, 0, (size_t)V * 4, stream);

    int gV = (V + 255) / 256;
    int gT = (T + 255) / 256;

    k_occ<<<gV, 256, 0, stream>>>(sdf, occ, V);
    k_classify<<<gT, 256, 0, stream>>>(tet, occ, ti8, tetPacked, T);
    run_scan(tetPacked, tetScan, T, blockSums, meta + 0, stream);
    k_count<<<gT, 256, 0, stream>>>(tet, ti8, bucketCnt, T);
    run_scan(bucketCnt, bucketStart, V, blockSums, meta + 1, stream);
    k_fill<<<gT, 256, 0, stream>>>(tet, ti8, bucketStart, cursor, maxArr, T);
    k_sortdedup<<<gV, 256, 0, stream>>>(bucketStart, bucketCnt, maxArr, occ, packedUC, V);
    run_scan(packedUC, ucScan, V, blockSums, meta + 2, stream);
    k_verts_map<<<gV, 256, 0, stream>>>(bucketStart, packedUC, ucScan, maxArr, mapArr,
                                        occ, pos, sdf, out, V);
    k_faces<<<gT, 256, 0, stream>>>(tet, ti8, tetScan, bucketStart, packedUC,
                                    maxArr, mapArr, meta, out, T, Ngrid, uvFloats);
    int gUV = (Ngrid * Ngrid + 255) / 256;
    k_uvs<<<gUV, 256, 0, stream>>>(out, meta, Ngrid);
}

// Round 2
// 913.838 us; speedup vs baseline: 2.6786x; 2.6786x over previous
//
#include <hip/hip_runtime.h>
#include <cmath>

typedef unsigned long long u64;
typedef unsigned int u32;
typedef unsigned short u16;
typedef unsigned char u8;

#define SCAN_BLOCK 256
#define SCAN_ELEMS 8
#define SCAN_TILE (SCAN_BLOCK * SCAN_ELEMS)

__constant__ int d_NUMTRI[16] = {0,1,1,2,1,2,2,1,1,2,2,1,2,1,1,0};
__constant__ int d_TRI[16][6] = {
 {-1,-1,-1,-1,-1,-1},{1,0,2,-1,-1,-1},{4,0,3,-1,-1,-1},{1,4,2,1,3,4},
 {3,1,5,-1,-1,-1},{2,3,0,2,5,3},{1,4,0,1,5,4},{4,2,5,-1,-1,-1},
 {4,5,2,-1,-1,-1},{4,1,0,4,5,1},{3,2,0,3,5,2},{1,3,5,-1,-1,-1},
 {4,1,2,4,3,1},{3,0,4,-1,-1,-1},{2,0,1,-1,-1,-1},{-1,-1,-1,-1,-1,-1}};
__constant__ int d_E0[6] = {0,0,0,1,1,2};
__constant__ int d_E1[6] = {1,2,3,2,3,3};

// ---------------- scans (exclusive), templated on element type ----------------
template <typename T>
__global__ void scanA_t(const T* in, T* out, int n, T* blockSums) {
    __shared__ T tsum[SCAN_BLOCK];
    int tbase = blockIdx.x * SCAN_TILE + threadIdx.x * SCAN_ELEMS;
    T vals[SCAN_ELEMS];
    T run = 0;
    for (int k = 0; k < SCAN_ELEMS; ++k) {
        int i = tbase + k;
        T v = (i < n) ? in[i] : (T)0;
        vals[k] = run;
        run += v;
    }
    tsum[threadIdx.x] = run;
    __syncthreads();
    for (int off = 1; off < SCAN_BLOCK; off <<= 1) {
        T v = (threadIdx.x >= (unsigned)off) ? tsum[threadIdx.x - off] : (T)0;
        __syncthreads();
        tsum[threadIdx.x] += v;
        __syncthreads();
    }
    T texcl = (threadIdx.x == 0) ? (T)0 : tsum[threadIdx.x - 1];
    for (int k = 0; k < SCAN_ELEMS; ++k) {
        int i = tbase + k;
        if (i < n) out[i] = texcl + vals[k];
    }
    if (threadIdx.x == SCAN_BLOCK - 1) blockSums[blockIdx.x] = tsum[SCAN_BLOCK - 1];
}

template <typename T>
__global__ void scanB_t(T* bs, int nb, T* totalOut) {
    __shared__ T sh[2048];
    for (int i = threadIdx.x; i < 2048; i += 256) sh[i] = (i < nb) ? bs[i] : (T)0;
    __syncthreads();
    for (int off = 1; off < 2048; off <<= 1) {
        T v[8];
        for (int k = 0; k < 8; ++k) {
            int i = threadIdx.x + k * 256;
            v[k] = (i >= off) ? sh[i - off] : (T)0;
        }
        __syncthreads();
        for (int k = 0; k < 8; ++k) sh[threadIdx.x + k * 256] += v[k];
        __syncthreads();
    }
    for (int i = threadIdx.x; i < nb; i += 256) bs[i] = (i == 0) ? (T)0 : sh[i - 1];
    if (threadIdx.x == 0 && totalOut) *totalOut = (nb > 0) ? sh[nb - 1] : (T)0;
}

template <typename T>
__global__ void scanC_t(T* out, int n, const T* bs) {
    int base = blockIdx.x * SCAN_TILE;
    T add = bs[blockIdx.x];
    int end = base + SCAN_TILE; if (end > n) end = n;
    for (int i = base + threadIdx.x; i < end; i += SCAN_BLOCK) out[i] += add;
}

// ---------------- pipeline kernels ----------------
__global__ void k_occ(const float* sdf, u32* occ, int V) {
    int i = blockIdx.x * 256 + threadIdx.x;
    if (i < V) occ[i] = (sdf[i] > 0.0f) ? 1u : 0u;
}

__global__ void k_classify(const int* tet, const u32* occ, u8* ti8, u64* tetPacked, int T) {
    int t = blockIdx.x * 256 + threadIdx.x;
    if (t >= T) return;
    int4 q = reinterpret_cast<const int4*>(tet)[t];
    int ti = (int)occ[q.x] | ((int)occ[q.y] << 1) | ((int)occ[q.z] << 2) | ((int)occ[q.w] << 3);
    ti8[t] = (u8)ti;
    int nt = d_NUMTRI[ti];
    tetPacked[t] = ((u64)(nt == 1 ? 1 : 0) << 21) | (u64)(nt == 2 ? 1 : 0);
}

__global__ void k_count(const int* tet, const u8* ti8, u32* bucketCnt, int T) {
    int t = blockIdx.x * 256 + threadIdx.x;
    if (t >= T) return;
    int ti = ti8[t];
    if (d_NUMTRI[ti] == 0) return;
    int4 q = reinterpret_cast<const int4*>(tet)[t];
    int idx[4] = {q.x, q.y, q.z, q.w};
    #pragma unroll
    for (int e = 0; e < 6; ++e) {
        int a = idx[d_E0[e]], b = idx[d_E1[e]];
        int mn = a < b ? a : b;
        atomicAdd(&bucketCnt[mn], 1u);
    }
}

__global__ void k_fill(const int* tet, const u8* ti8, const u32* bucketStart, u32* cursor,
                       u64* pairArr, int T) {
    int t = blockIdx.x * 256 + threadIdx.x;
    if (t >= T) return;
    int ti = ti8[t];
    if (d_NUMTRI[ti] == 0) return;
    int4 q = reinterpret_cast<const int4*>(tet)[t];
    int idx[4] = {q.x, q.y, q.z, q.w};
    #pragma unroll
    for (int e = 0; e < 6; ++e) {
        int a = idx[d_E0[e]], b = idx[d_E1[e]];
        int mn = a < b ? a : b;
        int mx = a < b ? b : a;
        u32 slot = atomicAdd(&cursor[mn], 1u);
        u32 inst = (u32)(6 * t + e);
        pairArr[(long long)bucketStart[mn] + slot] = ((u64)(u32)mx << 32) | (u64)inst;
    }
}

// One 64-lane wave (= one block) per bucket. LDS rank-sort + ballot dedup.
// Writes: unique sorted max-list in place over pairArr (as ints), per-instance
// compact map instMap[inst] = (bucket<<14)|crossRank or 0xFFFFFFFF, counts.
__global__ __launch_bounds__(64) void k_sortdedup(
    const u32* bucketCnt, const u32* bucketStart, u64* pairArr,
    const u32* occ, u32* instMap, u16* uCnt, u32* crossCnt, int V)
{
    int v = blockIdx.x;
    if (v >= V) return;
    int lane = threadIdx.x;
    int n = (int)bucketCnt[v];
    if (n == 0) { if (lane == 0) { uCnt[v] = 0; crossCnt[v] = 0; } return; }
    long long start = (long long)bucketStart[v];
    int* uniqOut = (int*)(pairArr + start);
    u32 occv = occ[v];

    if (n <= 256) {
        __shared__ u64 sk[256];
        __shared__ u64 ss[256];
        int chunks = (n + 63) >> 6;
        u64 key[4];
        #pragma unroll
        for (int c = 0; c < 4; ++c) {
            if (c < chunks) {
                int i = (c << 6) + lane;
                key[c] = (i < n) ? pairArr[start + i] : ~0ull;
                sk[(c << 6) + lane] = key[c];
            }
        }
        __syncthreads();
        int rank[4] = {0, 0, 0, 0};
        for (int j = 0; j < n; ++j) {
            u64 kj = sk[j];
            #pragma unroll
            for (int c = 0; c < 4; ++c)
                if (c < chunks) rank[c] += (kj < key[c]) ? 1 : 0;
        }
        #pragma unroll
        for (int c = 0; c < 4; ++c) {
            if (c < chunks) { int i = (c << 6) + lane; if (i < n) ss[rank[c]] = key[c]; }
        }
        __syncthreads();
        int carryU = 0, carryC = 0;
        for (int c = 0; c < chunks; ++c) {
            int i = (c << 6) + lane;
            bool valid = i < n;
            u64 k = ss[i];                      // i<256 in-bounds; invalid slots hold ~0
            int mx = (int)(k >> 32);
            u32 inst = (u32)k;
            int mxs = valid ? mx : 0;
            bool nf = valid && (i == 0 || (int)(ss[i - 1] >> 32) != mx);
            bool cross = valid && ((occv ^ occ[mxs]) != 0u);
            bool cf = nf && cross;
            u64 mnf = __ballot(nf);
            u64 mcf = __ballot(cf);
            u64 incl = (2ull << lane) - 1ull;   // lane 63 wraps to all-ones, correct
            int uIncl = carryU + __popcll(mnf & incl);
            int cIncl = carryC + __popcll(mcf & incl);
            if (valid) {
                if (nf) uniqOut[uIncl - 1] = mx;
                instMap[inst] = cross ? (u32)(((u32)v << 14) | (u32)(cIncl - 1))
                                      : 0xFFFFFFFFu;
            }
            carryU += __popcll(mnf);
            carryC += __popcll(mcf);
        }
        if (lane == 0) { uCnt[v] = (u16)carryU; crossCnt[v] = (u32)carryC; }
    } else if (lane == 0) {
        // fallback for oversized buckets (never hit at these sizes, kept for safety)
        for (int i = 1; i < n; ++i) {
            u64 kk = pairArr[start + i];
            int j = i - 1;
            while (j >= 0 && pairArr[start + j] > kk) {
                pairArr[start + j + 1] = pairArr[start + j]; --j;
            }
            pairArr[start + j + 1] = kk;
        }
        int uc = 0, cc = 0, prev = -1, curRank = 0;
        bool curCross = false;
        for (int i = 0; i < n; ++i) {
            u64 k = pairArr[start + i];
            int mx = (int)(k >> 32);
            u32 inst = (u32)k;
            if (mx != prev) {
                prev = mx;
                curCross = (occv ^ occ[mx]) != 0u;
                uniqOut[uc++] = mx;          // writes trail reads: safe in-place
                if (curCross) { curRank = cc; cc++; }
            }
            instMap[inst] = curCross ? (u32)(((u32)v << 14) | (u32)curRank) : 0xFFFFFFFFu;
        }
        uCnt[v] = (u16)uc;
        crossCnt[v] = (u32)cc;
    }
}

// One wave per bucket; lane per unique edge; ballot-prefix crossing ranks.
__global__ __launch_bounds__(64) void k_verts(
    const u16* uCnt, const u32* bucketStart, const u64* pairArr,
    const u32* crossScan, const u32* occ,
    const float* pos, const float* sdf, float* out, int V)
{
    int v = blockIdx.x;
    if (v >= V) return;
    int lane = threadIdx.x;
    int u = (int)uCnt[v];
    if (u == 0) return;
    long long start = (long long)bucketStart[v];
    const int* uniq = (const int*)(pairArr + start);
    int cBase = (int)crossScan[v];
    u32 occv = occ[v];
    float s0 = sdf[v];
    float p0x = pos[3 * v], p0y = pos[3 * v + 1], p0z = pos[3 * v + 2];
    int carry = 0;
    int chunks = (u + 63) >> 6;
    for (int c = 0; c < chunks; ++c) {
        int i = (c << 6) + lane;
        bool valid = i < u;
        int b = valid ? uniq[i] : 0;
        bool cross = valid && ((occv ^ occ[b]) != 0u);
        u64 m = __ballot(cross);
        int r = carry + __popcll(m & ((1ull << lane) - 1ull));
        if (cross) {
            long long k = cBase + r;
            float s1 = sdf[b];
            float d = s0 - s1;
            float w0 = -s1 / d, w1 = s0 / d;
            out[3 * k + 0] = p0x * w0 + pos[3 * b + 0] * w1;
            out[3 * k + 1] = p0y * w0 + pos[3 * b + 1] * w1;
            out[3 * k + 2] = p0z * w0 + pos[3 * b + 2] * w1;
        }
        carry += __popcll(m);
    }
}

__global__ void k_faces(const u8* ti8, const u64* tetScan, const u32* instMap,
                        const u32* crossScan, const u64* meta0, const u32* NePtr,
                        float* out, int T, int Ngrid, long long uvFloats)
{
    int t = blockIdx.x * 256 + threadIdx.x;
    if (t >= T) return;
    int ti = ti8[t];
    int nt = d_NUMTRI[ti];
    if (nt == 0) return;

    u64 tot = *meta0;
    int C1 = (int)((tot >> 21) & 0x1fffffull);
    int C2 = (int)(tot & 0x1fffffull);
    int Ne = (int)*NePtr;
    long long facesBase = 3LL * Ne;
    long long F = (long long)C1 + 2LL * C2;
    long long uvIdxBase = facesBase + 3LL * F + uvFloats;

    int emap[6];
    #pragma unroll
    for (int e = 0; e < 6; ++e) {
        u32 m = instMap[6 * t + e];
        if (m != 0xFFFFFFFFu) {
            int bv = (int)(m >> 14);
            emap[e] = (int)crossScan[bv] + (int)(m & 16383u);
        } else {
            emap[e] = -1;
        }
    }

    u64 sc = tetScan[t];
    int r1 = (int)((sc >> 21) & 0x1fffffull);
    int r2 = (int)(sc & 0x1fffffull);
    int tet_idx = (t / Ngrid) * Ngrid + (t % Ngrid);
    const int* row = d_TRI[ti];

    if (nt == 1) {
        long long f = r1;
        out[facesBase + 3 * f + 0] = (float)emap[row[0]];
        out[facesBase + 3 * f + 1] = (float)emap[row[1]];
        out[facesBase + 3 * f + 2] = (float)emap[row[2]];
        out[uvIdxBase + 3 * f + 0] = (float)(4 * tet_idx);
        out[uvIdxBase + 3 * f + 1] = (float)(4 * tet_idx + 1);
        out[uvIdxBase + 3 * f + 2] = (float)(4 * tet_idx + 2);
    } else {
        long long f0 = (long long)C1 + 2LL * r2;
        out[facesBase + 3 * f0 + 0] = (float)emap[row[0]];
        out[facesBase + 3 * f0 + 1] = (float)emap[row[1]];
        out[facesBase + 3 * f0 + 2] = (float)emap[row[2]];
        out[facesBase + 3 * (f0 + 1) + 0] = (float)emap[row[3]];
        out[facesBase + 3 * (f0 + 1) + 1] = (float)emap[row[4]];
        out[facesBase + 3 * (f0 + 1) + 2] = (float)emap[row[5]];
        out[uvIdxBase + 3 * f0 + 0] = (float)(4 * tet_idx);
        out[uvIdxBase + 3 * f0 + 1] = (float)(4 * tet_idx + 1);
        out[uvIdxBase + 3 * f0 + 2] = (float)(4 * tet_idx + 2);
        out[uvIdxBase + 3 * (f0 + 1) + 0] = (float)(4 * tet_idx);
        out[uvIdxBase + 3 * (f0 + 1) + 1] = (float)(4 * tet_idx + 2);
        out[uvIdxBase + 3 * (f0 + 1) + 2] = (float)(4 * tet_idx + 3);
    }
}

__global__ void k_uvs(float* out, const u64* meta0, const u32* NePtr, int Ngrid) {
    int c = blockIdx.x * 256 + threadIdx.x;
    int total = Ngrid * Ngrid;
    if (c >= total) return;
    u64 tot = *meta0;
    int C1 = (int)((tot >> 21) & 0x1fffffull);
    int C2 = (int)(tot & 0x1fffffull);
    int Ne = (int)*NePtr;
    long long uvBase = 3LL * Ne + 3LL * ((long long)C1 + 2LL * C2);
    int i = c / Ngrid, j = c % Ngrid;
    double step = (Ngrid > 1) ? (1.0 - 1.0 / (double)Ngrid) / (double)(Ngrid - 1) : 0.0;
    float x = (float)((double)j * step);
    float y = (float)((double)i * step);
    float pad = (float)(0.9 / (double)Ngrid);
    long long o = uvBase + 8LL * c;
    out[o + 0] = x;       out[o + 1] = y;
    out[o + 2] = x + pad; out[o + 3] = y;
    out[o + 4] = x + pad; out[o + 5] = y + pad;
    out[o + 6] = x;       out[o + 7] = y + pad;
}

// ---------------- host ----------------
template <typename T>
static void run_scan_t(const T* in, T* out, int n, T* blockSums, T* totalOut,
                       hipStream_t stream) {
    int nb = (n + SCAN_TILE - 1) / SCAN_TILE;
    scanA_t<T><<<nb, SCAN_BLOCK, 0, stream>>>(in, out, n, blockSums);
    scanB_t<T><<<1, 256, 0, stream>>>(blockSums, nb, totalOut);
    scanC_t<T><<<nb, SCAN_BLOCK, 0, stream>>>(out, n, blockSums);
}

extern "C" void kernel_launch(void* const* d_in, const int* in_sizes, int n_in,
                              void* d_out, int out_size, void* d_ws, size_t ws_size,
                              hipStream_t stream) {
    const float* pos = (const float*)d_in[0];
    const float* sdf = (const float*)d_in[1];
    const int* tet = (const int*)d_in[2];
    int V = in_sizes[1];
    int T = in_sizes[2] / 4;
    float* out = (float*)d_out;

    char* p = (char*)d_ws;
    auto alloc = [&](size_t bytes) -> void* {
        void* r = (void*)p;
        p += (bytes + 255) & ~(size_t)255;
        return r;
    };
    u32* occ         = (u32*)alloc((size_t)V * 4);
    u8*  ti8         = (u8*) alloc((size_t)T);
    u64* tetPacked   = (u64*)alloc((size_t)T * 8);
    u64* tetScan     = (u64*)alloc((size_t)T * 8);
    u32* bucketCnt   = (u32*)alloc((size_t)V * 4);
    u32* bucketStart = (u32*)alloc((size_t)V * 4);
    u32* cursor      = (u32*)alloc((size_t)V * 4);
    u16* uCnt        = (u16*)alloc((size_t)V * 2);
    u32* crossCnt    = (u32*)alloc((size_t)V * 4);
    u32* crossScan   = (u32*)alloc((size_t)V * 4);
    u64* pairArr     = (u64*)alloc((size_t)6 * T * 8);   // unique list overlaid in place
    u32* instMap     = (u32*)alloc((size_t)6 * T * 4);
    u64* blockSums64 = (u64*)alloc(2048 * 8);
    u32* blockSums32 = (u32*)alloc(2048 * 4);
    u64* meta        = (u64*)alloc(16 * 8);
    u32* NePtr       = (u32*)(meta + 8);

    long long M = (2LL * T + 1) / 2;
    int Ngrid = (int)std::sqrt((double)M);
    while ((long long)Ngrid * Ngrid < M) ++Ngrid;
    if (Ngrid < 1) Ngrid = 1;
    long long uvFloats = 8LL * Ngrid * Ngrid;

    hipMemsetAsync(bucketCnt, 0, (size_t)V * 4, stream);
    hipMemsetAsync(cursor, 0, (size_t)V * 4, stream);

    int gV = (V + 255) / 256;
    int gT = (T + 255) / 256;

    k_occ<<<gV, 256, 0, stream>>>(sdf, occ, V);
    k_classify<<<gT, 256, 0, stream>>>(tet, occ, ti8, tetPacked, T);
    run_scan_t<u64>(tetPacked, tetScan, T, blockSums64, meta, stream);
    k_count<<<gT, 256, 0, stream>>>(tet, ti8, bucketCnt, T);
    run_scan_t<u32>(bucketCnt, bucketStart, V, blockSums32, nullptr, stream);
    k_fill<<<gT, 256, 0, stream>>>(tet, ti8, bucketStart, cursor, pairArr, T);
    k_sortdedup<<<V, 64, 0, stream>>>(bucketCnt, bucketStart, pairArr, occ,
                                      instMap, uCnt, crossCnt, V);
    run_scan_t<u32>(crossCnt, crossScan, V, blockSums32, NePtr, stream);
    k_verts<<<V, 64, 0, stream>>>(uCnt, bucketStart, pairArr, crossScan, occ,
                                  pos, sdf, out, V);
    k_faces<<<gT, 256, 0, stream>>>(ti8, tetScan, instMap, crossScan, meta, NePtr,
                                    out, T, Ngrid, uvFloats);
    int gUV = (Ngrid * Ngrid + 255) / 256;
    k_uvs<<<gUV, 256, 0, stream>>>(out, meta, NePtr, Ngrid);
}

// Round 4
// 847.182 us; speedup vs baseline: 2.8893x; 1.0787x over previous
//
#include <hip/hip_runtime.h>
#include <cmath>

typedef unsigned long long u64;
typedef unsigned int u32;
typedef unsigned char u8;

#define SCAN_BLOCK 256
#define SCAN_ELEMS 8
#define SCAN_TILE (SCAN_BLOCK * SCAN_ELEMS)

__constant__ int d_NUMTRI[16] = {0,1,1,2,1,2,2,1,1,2,2,1,2,1,1,0};
__constant__ int d_TRI[16][6] = {
 {-1,-1,-1,-1,-1,-1},{1,0,2,-1,-1,-1},{4,0,3,-1,-1,-1},{1,4,2,1,3,4},
 {3,1,5,-1,-1,-1},{2,3,0,2,5,3},{1,4,0,1,5,4},{4,2,5,-1,-1,-1},
 {4,5,2,-1,-1,-1},{4,1,0,4,5,1},{3,2,0,3,5,2},{1,3,5,-1,-1,-1},
 {4,1,2,4,3,1},{3,0,4,-1,-1,-1},{2,0,1,-1,-1,-1},{-1,-1,-1,-1,-1,-1}};
__constant__ int d_E0[6] = {0,0,0,1,1,2};
__constant__ int d_E1[6] = {1,2,3,2,3,3};

// ---------------- exclusive scan, templated element type ----------------
// NOTE: the tet m1/m2 scan MUST be u64 — running m1 total needs 19 bits and is
// packed at bit 21 (19+21=40 bits overflows u32; that bug broke round 3).
template <typename T>
__global__ void scanA_t(const T* in, T* out, int n, T* blockSums) {
    __shared__ T tsum[SCAN_BLOCK];
    int tbase = blockIdx.x * SCAN_TILE + threadIdx.x * SCAN_ELEMS;
    T vals[SCAN_ELEMS];
    T run = 0;
    for (int k = 0; k < SCAN_ELEMS; ++k) {
        int i = tbase + k;
        T v = (i < n) ? in[i] : (T)0;
        vals[k] = run;
        run += v;
    }
    tsum[threadIdx.x] = run;
    __syncthreads();
    for (int off = 1; off < SCAN_BLOCK; off <<= 1) {
        T v = (threadIdx.x >= (unsigned)off) ? tsum[threadIdx.x - off] : (T)0;
        __syncthreads();
        tsum[threadIdx.x] += v;
        __syncthreads();
    }
    T texcl = (threadIdx.x == 0) ? (T)0 : tsum[threadIdx.x - 1];
    for (int k = 0; k < SCAN_ELEMS; ++k) {
        int i = tbase + k;
        if (i < n) out[i] = texcl + vals[k];
    }
    if (threadIdx.x == SCAN_BLOCK - 1) blockSums[blockIdx.x] = tsum[SCAN_BLOCK - 1];
}

template <typename T>
__global__ void scanB_t(T* bs, int nb, T* totalOut) {
    __shared__ T sh[2048];
    for (int i = threadIdx.x; i < 2048; i += 256) sh[i] = (i < nb) ? bs[i] : (T)0;
    __syncthreads();
    for (int off = 1; off < 2048; off <<= 1) {
        T v[8];
        for (int k = 0; k < 8; ++k) {
            int i = threadIdx.x + k * 256;
            v[k] = (i >= off) ? sh[i - off] : (T)0;
        }
        __syncthreads();
        for (int k = 0; k < 8; ++k) sh[threadIdx.x + k * 256] += v[k];
        __syncthreads();
    }
    for (int i = threadIdx.x; i < nb; i += 256) bs[i] = (i == 0) ? (T)0 : sh[i - 1];
    if (threadIdx.x == 0 && totalOut) *totalOut = (nb > 0) ? sh[nb - 1] : (T)0;
}

template <typename T>
__global__ void scanC_t(T* out, int n, const T* bs) {
    int base = blockIdx.x * SCAN_TILE;
    T add = bs[blockIdx.x];
    int end = base + SCAN_TILE; if (end > n) end = n;
    for (int i = base + threadIdx.x; i < end; i += SCAN_BLOCK) out[i] += add;
}

// ---------------- pipeline ----------------
__global__ void k_occ(const float* sdf, u32* occ, int V) {
    int i = blockIdx.x * 256 + threadIdx.x;
    if (i < V) occ[i] = (sdf[i] > 0.0f) ? 1u : 0u;
}

// fused classify + crossing-edge bucket count (crossing test comes free from ti)
__global__ void k_classify_count(const int* tet, const u32* occ, u8* ti8, u64* tetPack,
                                 u32* bucketCnt, int T) {
    int t = blockIdx.x * 256 + threadIdx.x;
    if (t >= T) return;
    int4 q = reinterpret_cast<const int4*>(tet)[t];
    int ti = (int)occ[q.x] | ((int)occ[q.y] << 1) | ((int)occ[q.z] << 2) | ((int)occ[q.w] << 3);
    ti8[t] = (u8)ti;
    int nt = d_NUMTRI[ti];
    tetPack[t] = ((u64)(nt == 1 ? 1 : 0) << 21) | (u64)(nt == 2 ? 1 : 0);
    if (nt == 0) return;
    int idx[4] = {q.x, q.y, q.z, q.w};
    #pragma unroll
    for (int e = 0; e < 6; ++e) {
        int e0 = d_E0[e], e1 = d_E1[e];
        if (((ti >> e0) ^ (ti >> e1)) & 1) {
            int a = idx[e0], b = idx[e1];
            atomicAdd(&bucketCnt[a < b ? a : b], 1u);
        }
    }
}

// crossing edges only: scatter max-endpoint (u32) into per-min-vertex bucket
__global__ void k_fill(const int* tet, const u8* ti8, const u32* bucketStart, u32* cursor,
                       u32* maxArr, int T) {
    int t = blockIdx.x * 256 + threadIdx.x;
    if (t >= T) return;
    int ti = ti8[t];
    if (d_NUMTRI[ti] == 0) return;
    int4 q = reinterpret_cast<const int4*>(tet)[t];
    int idx[4] = {q.x, q.y, q.z, q.w};
    #pragma unroll
    for (int e = 0; e < 6; ++e) {
        int e0 = d_E0[e], e1 = d_E1[e];
        if (((ti >> e0) ^ (ti >> e1)) & 1) {
            int a = idx[e0], b = idx[e1];
            int mn = a < b ? a : b;
            int mx = a < b ? b : a;
            u32 slot = atomicAdd(&cursor[mn], 1u);
            maxArr[(long long)bucketStart[mn] + slot] = (u32)mx;
        }
    }
}

// one wave per bucket: LDS rank-sort (tie-break by index) + dedup in place
__global__ __launch_bounds__(64) void k_sortdedup(
    const u32* bucketCnt, const u32* bucketStart, u32* maxArr, u32* crossCnt, int V)
{
    int v = blockIdx.x;
    if (v >= V) return;
    int lane = threadIdx.x;
    int n = (int)bucketCnt[v];
    if (n == 0) { if (lane == 0) crossCnt[v] = 0; return; }
    long long start = (long long)bucketStart[v];

    if (n <= 256) {
        __shared__ u32 sk[256];
        __shared__ u32 ss[256];
        int chunks = (n + 63) >> 6;
        u32 key[4];
        #pragma unroll
        for (int c = 0; c < 4; ++c) {
            if (c < chunks) {
                int i = (c << 6) + lane;
                key[c] = (i < n) ? maxArr[start + i] : 0xFFFFFFFFu;
                sk[(c << 6) + lane] = key[c];
            }
        }
        __syncthreads();
        int rank[4] = {0, 0, 0, 0};
        for (int j = 0; j < n; ++j) {
            u32 kj = sk[j];
            #pragma unroll
            for (int c = 0; c < 4; ++c) {
                if (c < chunks) {
                    int i = (c << 6) + lane;
                    rank[c] += (kj < key[c] || (kj == key[c] && j < i)) ? 1 : 0;
                }
            }
        }
        #pragma unroll
        for (int c = 0; c < 4; ++c) {
            if (c < chunks) { int i = (c << 6) + lane; if (i < n) ss[rank[c]] = key[c]; }
        }
        __syncthreads();
        int carryU = 0;
        for (int c = 0; c < chunks; ++c) {
            int i = (c << 6) + lane;
            bool valid = i < n;
            u32 k = ss[i < 256 ? i : 255];
            bool nf = valid && (i == 0 || ss[i - 1] != k);
            u64 mnf = __ballot(nf);
            u64 incl = (2ull << lane) - 1ull;   // lane 63 wraps to all-ones: correct
            int uIncl = carryU + __popcll(mnf & incl);
            if (nf) maxArr[start + uIncl - 1] = k;
            carryU += __popcll(mnf);
        }
        if (lane == 0) crossCnt[v] = (u32)carryU;
    } else if (lane == 0) {
        // safety fallback; not expected at these sizes
        for (int i = 1; i < n; ++i) {
            u32 kk = maxArr[start + i];
            int j = i - 1;
            while (j >= 0 && maxArr[start + j] > kk) {
                maxArr[start + j + 1] = maxArr[start + j]; --j;
            }
            maxArr[start + j + 1] = kk;
        }
        int uc = 0; u32 prev = 0xFFFFFFFFu;
        for (int i = 0; i < n; ++i) {
            u32 k = maxArr[start + i];
            if (k != prev) { maxArr[start + uc] = k; ++uc; prev = k; }
        }
        crossCnt[v] = (u32)uc;
    }
}

// one wave per bucket; lane i -> unique crossing edge i -> vertex crossScan[v]+i
__global__ __launch_bounds__(64) void k_verts(
    const u32* crossCnt, const u32* bucketStart, const u32* maxArr, const u32* crossScan,
    const float* pos, const float* sdf, float* out, int V)
{
    int v = blockIdx.x;
    if (v >= V) return;
    int lane = threadIdx.x;
    int u = (int)crossCnt[v];
    if (u == 0) return;
    long long start = (long long)bucketStart[v];
    int cBase = (int)crossScan[v];
    float s0 = sdf[v];
    float p0x = pos[3 * v], p0y = pos[3 * v + 1], p0z = pos[3 * v + 2];
    for (int i = lane; i < u; i += 64) {
        int b = (int)maxArr[start + i];
        long long k = cBase + i;
        float s1 = sdf[b];
        float d = s0 - s1;
        float w0 = -s1 / d, w1 = s0 / d;
        out[3 * k + 0] = p0x * w0 + pos[3 * b + 0] * w1;
        out[3 * k + 1] = p0y * w0 + pos[3 * b + 1] * w1;
        out[3 * k + 2] = p0z * w0 + pos[3 * b + 2] * w1;
    }
}

// faces + uv_idx; edge->vertex id via linear scan of the (small) sorted bucket
__global__ void k_faces(const int* tet, const u8* ti8, const u64* tetScan,
                        const u32* bucketStart, const u32* crossCnt, const u32* maxArr,
                        const u32* crossScan, const u64* meta0, const u32* NePtr,
                        float* out, int T, int Ngrid, long long uvFloats)
{
    int t = blockIdx.x * 256 + threadIdx.x;
    if (t >= T) return;
    int ti = ti8[t];
    int nt = d_NUMTRI[ti];
    if (nt == 0) return;

    u64 tot = *meta0;
    int C1 = (int)((tot >> 21) & 0x1fffffull);
    int C2 = (int)(tot & 0x1fffffull);
    int Ne = (int)*NePtr;
    long long facesBase = 3LL * Ne;
    long long F = (long long)C1 + 2LL * C2;
    long long uvIdxBase = facesBase + 3LL * F + uvFloats;

    int4 q = reinterpret_cast<const int4*>(tet)[t];
    int idx[4] = {q.x, q.y, q.z, q.w};
    const int* row = d_TRI[ti];

    int emap[6];
    unsigned done = 0;
    float fv[6];
    #pragma unroll
    for (int j = 0; j < 6; ++j) {
        if (j >= 3 * nt) break;
        int e = row[j];
        if (!((done >> e) & 1)) {
            done |= 1u << e;
            int a = idx[d_E0[e]], b = idx[d_E1[e]];
            if (a > b) { int tmp = a; a = b; b = tmp; }
            long long s = (long long)bucketStart[a];
            int u = (int)crossCnt[a];
            int cnt = 0;
            for (int k = 0; k < u; ++k) cnt += ((int)maxArr[s + k] < b) ? 1 : 0;
            emap[e] = (int)crossScan[a] + cnt;
        }
        fv[j] = (float)emap[e];
    }

    u64 sc = tetScan[t];
    int r1 = (int)((sc >> 21) & 0x1fffffull);
    int r2 = (int)(sc & 0x1fffffull);
    int tet_idx = (t / Ngrid) * Ngrid + (t % Ngrid);

    if (nt == 1) {
        long long f = r1;
        out[facesBase + 3 * f + 0] = fv[0];
        out[facesBase + 3 * f + 1] = fv[1];
        out[facesBase + 3 * f + 2] = fv[2];
        out[uvIdxBase + 3 * f + 0] = (float)(4 * tet_idx);
        out[uvIdxBase + 3 * f + 1] = (float)(4 * tet_idx + 1);
        out[uvIdxBase + 3 * f + 2] = (float)(4 * tet_idx + 2);
    } else {
        long long f0 = (long long)C1 + 2LL * r2;
        out[facesBase + 3 * f0 + 0] = fv[0];
        out[facesBase + 3 * f0 + 1] = fv[1];
        out[facesBase + 3 * f0 + 2] = fv[2];
        out[facesBase + 3 * (f0 + 1) + 0] = fv[3];
        out[facesBase + 3 * (f0 + 1) + 1] = fv[4];
        out[facesBase + 3 * (f0 + 1) + 2] = fv[5];
        out[uvIdxBase + 3 * f0 + 0] = (float)(4 * tet_idx);
        out[uvIdxBase + 3 * f0 + 1] = (float)(4 * tet_idx + 1);
        out[uvIdxBase + 3 * f0 + 2] = (float)(4 * tet_idx + 2);
        out[uvIdxBase + 3 * (f0 + 1) + 0] = (float)(4 * tet_idx);
        out[uvIdxBase + 3 * (f0 + 1) + 1] = (float)(4 * tet_idx + 2);
        out[uvIdxBase + 3 * (f0 + 1) + 2] = (float)(4 * tet_idx + 3);
    }
}

__global__ void k_uvs(float* out, const u64* meta0, const u32* NePtr, int Ngrid) {
    int c = blockIdx.x * 256 + threadIdx.x;
    int total = Ngrid * Ngrid;
    if (c >= total) return;
    u64 tot = *meta0;
    int C1 = (int)((tot >> 21) & 0x1fffffull);
    int C2 = (int)(tot & 0x1fffffull);
    int Ne = (int)*NePtr;
    long long uvBase = 3LL * Ne + 3LL * ((long long)C1 + 2LL * C2);
    int i = c / Ngrid, j = c % Ngrid;
    double step = (Ngrid > 1) ? (1.0 - 1.0 / (double)Ngrid) / (double)(Ngrid - 1) : 0.0;
    float x = (float)((double)j * step);
    float y = (float)((double)i * step);
    float pad = (float)(0.9 / (double)Ngrid);
    long long o = uvBase + 8LL * c;
    out[o + 0] = x;       out[o + 1] = y;
    out[o + 2] = x + pad; out[o + 3] = y;
    out[o + 4] = x + pad; out[o + 5] = y + pad;
    out[o + 6] = x;       out[o + 7] = y + pad;
}

// ---------------- host ----------------
template <typename T>
static void run_scan_t(const T* in, T* out, int n, T* blockSums, T* totalOut,
                       hipStream_t stream) {
    int nb = (n + SCAN_TILE - 1) / SCAN_TILE;
    scanA_t<T><<<nb, SCAN_BLOCK, 0, stream>>>(in, out, n, blockSums);
    scanB_t<T><<<1, 256, 0, stream>>>(blockSums, nb, totalOut);
    scanC_t<T><<<nb, SCAN_BLOCK, 0, stream>>>(out, n, blockSums);
}

extern "C" void kernel_launch(void* const* d_in, const int* in_sizes, int n_in,
                              void* d_out, int out_size, void* d_ws, size_t ws_size,
                              hipStream_t stream) {
    const float* pos = (const float*)d_in[0];
    const float* sdf = (const float*)d_in[1];
    const int* tet = (const int*)d_in[2];
    int V = in_sizes[1];
    int T = in_sizes[2] / 4;
    float* out = (float*)d_out;

    char* p = (char*)d_ws;
    auto alloc = [&](size_t bytes) -> void* {
        void* r = (void*)p;
        p += (bytes + 255) & ~(size_t)255;
        return r;
    };
    u32* occ         = (u32*)alloc((size_t)V * 4);
    u8*  ti8         = (u8*) alloc((size_t)T);
    u64* tetPack     = (u64*)alloc((size_t)T * 8);
    u64* tetScan     = (u64*)alloc((size_t)T * 8);
    u32* bucketCnt   = (u32*)alloc((size_t)V * 4);
    u32* bucketStart = (u32*)alloc((size_t)V * 4);
    u32* cursor      = (u32*)alloc((size_t)V * 4);
    u32* crossCnt    = (u32*)alloc((size_t)V * 4);
    u32* crossScan   = (u32*)alloc((size_t)V * 4);
    u32* maxArr      = (u32*)alloc((size_t)6 * T * 4);
    u64* blockSums64 = (u64*)alloc(2048 * 8);
    u32* blockSums32 = (u32*)alloc(2048 * 4);
    u64* meta64      = (u64*)alloc(8 * 8);
    u32* NePtr       = (u32*)(meta64 + 4);

    long long M = (2LL * T + 1) / 2;
    int Ngrid = (int)std::sqrt((double)M);
    while ((long long)Ngrid * Ngrid < M) ++Ngrid;
    if (Ngrid < 1) Ngrid = 1;
    long long uvFloats = 8LL * Ngrid * Ngrid;

    hipMemsetAsync(bucketCnt, 0, (size_t)V * 4, stream);
    hipMemsetAsync(cursor, 0, (size_t)V * 4, stream);

    int gV = (V + 255) / 256;
    int gT = (T + 255) / 256;

    k_occ<<<gV, 256, 0, stream>>>(sdf, occ, V);
    k_classify_count<<<gT, 256, 0, stream>>>(tet, occ, ti8, tetPack, bucketCnt, T);
    run_scan_t<u64>(tetPack, tetScan, T, blockSums64, meta64, stream);
    run_scan_t<u32>(bucketCnt, bucketStart, V, blockSums32, nullptr, stream);
    k_fill<<<gT, 256, 0, stream>>>(tet, ti8, bucketStart, cursor, maxArr, T);
    k_sortdedup<<<V, 64, 0, stream>>>(bucketCnt, bucketStart, maxArr, crossCnt, V);
    run_scan_t<u32>(crossCnt, crossScan, V, blockSums32, NePtr, stream);
    k_verts<<<V, 64, 0, stream>>>(crossCnt, bucketStart, maxArr, crossScan,
                                  pos, sdf, out, V);
    k_faces<<<gT, 256, 0, stream>>>(tet, ti8, tetScan, bucketStart, crossCnt, maxArr,
                                    crossScan, meta64, NePtr, out, T, Ngrid, uvFloats);
    int gUV = (Ngrid * Ngrid + 255) / 256;
    k_uvs<<<gUV, 256, 0, stream>>>(out, meta64, NePtr, Ngrid);
}

// Round 5
// 765.826 us; speedup vs baseline: 3.1963x; 1.1062x over previous
//
#include <hip/hip_runtime.h>
#include <cmath>

typedef unsigned long long u64;
typedef unsigned int u32;
typedef unsigned char u8;

#define SCAN_BLOCK 256
#define SCAN_ELEMS 8
#define SCAN_TILE (SCAN_BLOCK * SCAN_ELEMS)

__constant__ int d_NUMTRI[16] = {0,1,1,2,1,2,2,1,1,2,2,1,2,1,1,0};
__constant__ int d_TRI[16][6] = {
 {-1,-1,-1,-1,-1,-1},{1,0,2,-1,-1,-1},{4,0,3,-1,-1,-1},{1,4,2,1,3,4},
 {3,1,5,-1,-1,-1},{2,3,0,2,5,3},{1,4,0,1,5,4},{4,2,5,-1,-1,-1},
 {4,5,2,-1,-1,-1},{4,1,0,4,5,1},{3,2,0,3,5,2},{1,3,5,-1,-1,-1},
 {4,1,2,4,3,1},{3,0,4,-1,-1,-1},{2,0,1,-1,-1,-1},{-1,-1,-1,-1,-1,-1}};
__constant__ int d_E0[6] = {0,0,0,1,1,2};
__constant__ int d_E1[6] = {1,2,3,2,3,3};

// ---------------- exclusive scan, templated element type ----------------
// NOTE: tet m1/m2 scan MUST be u64 — running m1 total needs 19 bits packed at
// bit 21 (overflowed u32 in round 3).
template <typename T>
__global__ void scanA_t(const T* in, T* out, int n, T* blockSums) {
    __shared__ T tsum[SCAN_BLOCK];
    int tbase = blockIdx.x * SCAN_TILE + threadIdx.x * SCAN_ELEMS;
    T vals[SCAN_ELEMS];
    T run = 0;
    for (int k = 0; k < SCAN_ELEMS; ++k) {
        int i = tbase + k;
        T v = (i < n) ? in[i] : (T)0;
        vals[k] = run;
        run += v;
    }
    tsum[threadIdx.x] = run;
    __syncthreads();
    for (int off = 1; off < SCAN_BLOCK; off <<= 1) {
        T v = (threadIdx.x >= (unsigned)off) ? tsum[threadIdx.x - off] : (T)0;
        __syncthreads();
        tsum[threadIdx.x] += v;
        __syncthreads();
    }
    T texcl = (threadIdx.x == 0) ? (T)0 : tsum[threadIdx.x - 1];
    for (int k = 0; k < SCAN_ELEMS; ++k) {
        int i = tbase + k;
        if (i < n) out[i] = texcl + vals[k];
    }
    if (threadIdx.x == SCAN_BLOCK - 1) blockSums[blockIdx.x] = tsum[SCAN_BLOCK - 1];
}

template <typename T>
__global__ void scanB_t(T* bs, int nb, T* totalOut) {
    __shared__ T sh[2048];
    for (int i = threadIdx.x; i < 2048; i += 256) sh[i] = (i < nb) ? bs[i] : (T)0;
    __syncthreads();
    for (int off = 1; off < 2048; off <<= 1) {
        T v[8];
        for (int k = 0; k < 8; ++k) {
            int i = threadIdx.x + k * 256;
            v[k] = (i >= off) ? sh[i - off] : (T)0;
        }
        __syncthreads();
        for (int k = 0; k < 8; ++k) sh[threadIdx.x + k * 256] += v[k];
        __syncthreads();
    }
    for (int i = threadIdx.x; i < nb; i += 256) bs[i] = (i == 0) ? (T)0 : sh[i - 1];
    if (threadIdx.x == 0 && totalOut) *totalOut = (nb > 0) ? sh[nb - 1] : (T)0;
}

template <typename T>
__global__ void scanC_t(T* out, int n, const T* bs) {
    int base = blockIdx.x * SCAN_TILE;
    T add = bs[blockIdx.x];
    int end = base + SCAN_TILE; if (end > n) end = n;
    for (int i = base + threadIdx.x; i < end; i += SCAN_BLOCK) out[i] += add;
}

// ---------------- pipeline ----------------
// fused classify + crossing-edge bucket count (reads sdf signs directly)
__global__ void k_classify_count(const int* tet, const float* sdf, u8* ti8, u64* tetPack,
                                 u32* bucketCnt, int T) {
    int t = blockIdx.x * 256 + threadIdx.x;
    if (t >= T) return;
    int4 q = reinterpret_cast<const int4*>(tet)[t];
    int ti = (sdf[q.x] > 0.0f ? 1 : 0) | (sdf[q.y] > 0.0f ? 2 : 0) |
             (sdf[q.z] > 0.0f ? 4 : 0) | (sdf[q.w] > 0.0f ? 8 : 0);
    ti8[t] = (u8)ti;
    int nt = d_NUMTRI[ti];
    tetPack[t] = ((u64)(nt == 1 ? 1 : 0) << 21) | (u64)(nt == 2 ? 1 : 0);
    if (nt == 0) return;
    int idx[4] = {q.x, q.y, q.z, q.w};
    #pragma unroll
    for (int e = 0; e < 6; ++e) {
        int e0 = d_E0[e], e1 = d_E1[e];
        if (((ti >> e0) ^ (ti >> e1)) & 1) {
            int a = idx[e0], b = idx[e1];
            atomicAdd(&bucketCnt[a < b ? a : b], 1u);
        }
    }
}

// round bucket counts up to 16 u32s => every bucket starts 64B-aligned
__global__ void k_pad(const u32* bucketCnt, u32* padCnt, int V) {
    int v = blockIdx.x * 256 + threadIdx.x;
    if (v < V) padCnt[v] = (bucketCnt[v] + 15u) & ~15u;
}

// crossing edges only: scatter max-endpoint (u32) into per-min-vertex bucket
__global__ void k_fill(const int* tet, const u8* ti8, const u32* bucketStart, u32* cursor,
                       u32* maxArr, int T) {
    int t = blockIdx.x * 256 + threadIdx.x;
    if (t >= T) return;
    int ti = ti8[t];
    if (d_NUMTRI[ti] == 0) return;
    int4 q = reinterpret_cast<const int4*>(tet)[t];
    int idx[4] = {q.x, q.y, q.z, q.w};
    #pragma unroll
    for (int e = 0; e < 6; ++e) {
        int e0 = d_E0[e], e1 = d_E1[e];
        if (((ti >> e0) ^ (ti >> e1)) & 1) {
            int a = idx[e0], b = idx[e1];
            int mn = a < b ? a : b;
            int mx = a < b ? b : a;
            u32 slot = atomicAdd(&cursor[mn], 1u);
            maxArr[(long long)bucketStart[mn] + slot] = (u32)mx;
        }
    }
}

// one wave per bucket. n<=64: pure cross-lane (shfl rank + ds_permute scatter +
// ballot dedup), no LDS, no barriers. n<=256: LDS rank-sort. else serial.
__global__ __launch_bounds__(64) void k_sortdedup(
    const u32* bucketCnt, const u32* bucketStart, u32* maxArr, u32* crossCnt, int V)
{
    int v = blockIdx.x;
    if (v >= V) return;
    int lane = threadIdx.x;
    int n = (int)bucketCnt[v];
    if (n == 0) { if (lane == 0) crossCnt[v] = 0; return; }
    long long start = (long long)bucketStart[v];

    if (n <= 64) {
        u32 key = (lane < n) ? maxArr[start + lane] : 0xFFFFFFFFu;
        int rank = 0;
        #pragma unroll 16
        for (int j = 0; j < 64; ++j) {
            u32 kj = (u32)__shfl((int)key, j);
            rank += (kj < key || (kj == key && j < lane)) ? 1 : 0;
        }
        // scatter: lane 'rank' receives our key (rank is a 0..63 permutation)
        u32 sorted = (u32)__builtin_amdgcn_ds_permute(rank << 2, (int)key);
        u32 prev = (u32)__shfl((int)sorted, lane - 1);
        bool nf = (lane < n) && (lane == 0 || prev != sorted);
        u64 m = __ballot(nf);
        int idx = __popcll(m & ((1ull << lane) - 1ull));
        if (nf) maxArr[start + idx] = sorted;
        if (lane == 0) crossCnt[v] = (u32)__popcll(m);
    } else if (n <= 256) {
        __shared__ u32 sk[256];
        __shared__ u32 ss[256];
        int chunks = (n + 63) >> 6;
        u32 key[4];
        #pragma unroll
        for (int c = 0; c < 4; ++c) {
            if (c < chunks) {
                int i = (c << 6) + lane;
                key[c] = (i < n) ? maxArr[start + i] : 0xFFFFFFFFu;
                sk[(c << 6) + lane] = key[c];
            }
        }
        __syncthreads();
        int rank[4] = {0, 0, 0, 0};
        for (int j = 0; j < n; ++j) {
            u32 kj = sk[j];
            #pragma unroll
            for (int c = 0; c < 4; ++c) {
                if (c < chunks) {
                    int i = (c << 6) + lane;
                    rank[c] += (kj < key[c] || (kj == key[c] && j < i)) ? 1 : 0;
                }
            }
        }
        #pragma unroll
        for (int c = 0; c < 4; ++c) {
            if (c < chunks) { int i = (c << 6) + lane; if (i < n) ss[rank[c]] = key[c]; }
        }
        __syncthreads();
        int carryU = 0;
        for (int c = 0; c < chunks; ++c) {
            int i = (c << 6) + lane;
            bool valid = i < n;
            u32 k = ss[i < 256 ? i : 255];
            bool nf = valid && (i == 0 || ss[i - 1] != k);
            u64 mnf = __ballot(nf);
            u64 incl = (2ull << lane) - 1ull;
            int uIncl = carryU + __popcll(mnf & incl);
            if (nf) maxArr[start + uIncl - 1] = k;
            carryU += __popcll(mnf);
        }
        if (lane == 0) crossCnt[v] = (u32)carryU;
    } else if (lane == 0) {
        for (int i = 1; i < n; ++i) {
            u32 kk = maxArr[start + i];
            int j = i - 1;
            while (j >= 0 && maxArr[start + j] > kk) {
                maxArr[start + j + 1] = maxArr[start + j]; --j;
            }
            maxArr[start + j + 1] = kk;
        }
        int uc = 0; u32 prev = 0xFFFFFFFFu;
        for (int i = 0; i < n; ++i) {
            u32 k = maxArr[start + i];
            if (k != prev) { maxArr[start + uc] = k; ++uc; prev = k; }
        }
        crossCnt[v] = (u32)uc;
    }
}

// pack per-vertex lookup metadata: x=start, y=(u<<22)|crossScan  (1.6 MB total)
__global__ void k_metapack(const u32* bucketStart, const u32* crossCnt,
                           const u32* crossScan, uint2* meta2, int V) {
    int v = blockIdx.x * 256 + threadIdx.x;
    if (v < V) meta2[v] = make_uint2(bucketStart[v], (crossCnt[v] << 22) | crossScan[v]);
}

// one wave per bucket; lane i -> unique crossing edge i -> vertex crossScan[v]+i
__global__ __launch_bounds__(64) void k_verts(
    const u32* crossCnt, const u32* bucketStart, const u32* maxArr, const u32* crossScan,
    const float* pos, const float* sdf, float* out, int V)
{
    int v = blockIdx.x;
    if (v >= V) return;
    int lane = threadIdx.x;
    int u = (int)crossCnt[v];
    if (u == 0) return;
    long long start = (long long)bucketStart[v];
    int cBase = (int)crossScan[v];
    float s0 = sdf[v];
    float p0x = pos[3 * v], p0y = pos[3 * v + 1], p0z = pos[3 * v + 2];
    for (int i = lane; i < u; i += 64) {
        int b = (int)maxArr[start + i];
        long long k = cBase + i;
        float s1 = sdf[b];
        float d = s0 - s1;
        float w0 = -s1 / d, w1 = s0 / d;
        out[3 * k + 0] = p0x * w0 + pos[3 * b + 0] * w1;
        out[3 * k + 1] = p0y * w0 + pos[3 * b + 1] * w1;
        out[3 * k + 2] = p0z * w0 + pos[3 * b + 2] * w1;
    }
}

// faces + uv_idx; edge->vertex id via uint4 scan of 64B-aligned sorted bucket
__global__ void k_faces(const int* tet, const u8* ti8, const u64* tetScan,
                        const uint2* meta2, const u32* maxArr,
                        const u64* meta0, const u32* NePtr,
                        float* out, int T, int Ngrid, long long uvFloats)
{
    int t = blockIdx.x * 256 + threadIdx.x;
    if (t >= T) return;
    int ti = ti8[t];
    int nt = d_NUMTRI[ti];
    if (nt == 0) return;

    u64 tot = *meta0;
    int C1 = (int)((tot >> 21) & 0x1fffffull);
    int C2 = (int)(tot & 0x1fffffull);
    int Ne = (int)*NePtr;
    long long facesBase = 3LL * Ne;
    long long F = (long long)C1 + 2LL * C2;
    long long uvIdxBase = facesBase + 3LL * F + uvFloats;

    int4 q = reinterpret_cast<const int4*>(tet)[t];
    int idx[4] = {q.x, q.y, q.z, q.w};
    const int* row = d_TRI[ti];

    int emap[6];
    unsigned done = 0;
    float fv[6];
    #pragma unroll
    for (int j = 0; j < 6; ++j) {
        if (j >= 3 * nt) break;
        int e = row[j];
        if (!((done >> e) & 1)) {
            done |= 1u << e;
            int a = idx[d_E0[e]], b = idx[d_E1[e]];
            if (a > b) { int tmp = a; a = b; b = tmp; }
            uint2 m = meta2[a];
            int u = (int)(m.y >> 22);
            int base = (int)(m.y & 0x3FFFFFu);
            const uint4* bp = (const uint4*)(maxArr + m.x);  // 64B-aligned
            int cnt = 0;
            int nv = (u + 3) >> 2;
            for (int k4 = 0; k4 < nv; ++k4) {
                uint4 w = bp[k4];
                int b4 = k4 << 2;
                cnt += (b4 + 0 < u && (int)w.x < b) ? 1 : 0;
                cnt += (b4 + 1 < u && (int)w.y < b) ? 1 : 0;
                cnt += (b4 + 2 < u && (int)w.z < b) ? 1 : 0;
                cnt += (b4 + 3 < u && (int)w.w < b) ? 1 : 0;
            }
            emap[e] = base + cnt;
        }
        fv[j] = (float)emap[e];
    }

    u64 sc = tetScan[t];
    int r1 = (int)((sc >> 21) & 0x1fffffull);
    int r2 = (int)(sc & 0x1fffffull);
    int tet_idx = (t / Ngrid) * Ngrid + (t % Ngrid);

    if (nt == 1) {
        long long f = r1;
        out[facesBase + 3 * f + 0] = fv[0];
        out[facesBase + 3 * f + 1] = fv[1];
        out[facesBase + 3 * f + 2] = fv[2];
        out[uvIdxBase + 3 * f + 0] = (float)(4 * tet_idx);
        out[uvIdxBase + 3 * f + 1] = (float)(4 * tet_idx + 1);
        out[uvIdxBase + 3 * f + 2] = (float)(4 * tet_idx + 2);
    } else {
        long long f0 = (long long)C1 + 2LL * r2;
        out[facesBase + 3 * f0 + 0] = fv[0];
        out[facesBase + 3 * f0 + 1] = fv[1];
        out[facesBase + 3 * f0 + 2] = fv[2];
        out[facesBase + 3 * (f0 + 1) + 0] = fv[3];
        out[facesBase + 3 * (f0 + 1) + 1] = fv[4];
        out[facesBase + 3 * (f0 + 1) + 2] = fv[5];
        out[uvIdxBase + 3 * f0 + 0] = (float)(4 * tet_idx);
        out[uvIdxBase + 3 * f0 + 1] = (float)(4 * tet_idx + 1);
        out[uvIdxBase + 3 * f0 + 2] = (float)(4 * tet_idx + 2);
        out[uvIdxBase + 3 * (f0 + 1) + 0] = (float)(4 * tet_idx);
        out[uvIdxBase + 3 * (f0 + 1) + 1] = (float)(4 * tet_idx + 2);
        out[uvIdxBase + 3 * (f0 + 1) + 2] = (float)(4 * tet_idx + 3);
    }
}

__global__ void k_uvs(float* out, const u64* meta0, const u32* NePtr, int Ngrid) {
    int c = blockIdx.x * 256 + threadIdx.x;
    int total = Ngrid * Ngrid;
    if (c >= total) return;
    u64 tot = *meta0;
    int C1 = (int)((tot >> 21) & 0x1fffffull);
    int C2 = (int)(tot & 0x1fffffull);
    int Ne = (int)*NePtr;
    long long uvBase = 3LL * Ne + 3LL * ((long long)C1 + 2LL * C2);
    int i = c / Ngrid, j = c % Ngrid;
    double step = (Ngrid > 1) ? (1.0 - 1.0 / (double)Ngrid) / (double)(Ngrid - 1) : 0.0;
    float x = (float)((double)j * step);
    float y = (float)((double)i * step);
    float pad = (float)(0.9 / (double)Ngrid);
    long long o = uvBase + 8LL * c;
    out[o + 0] = x;       out[o + 1] = y;
    out[o + 2] = x + pad; out[o + 3] = y;
    out[o + 4] = x + pad; out[o + 5] = y + pad;
    out[o + 6] = x;       out[o + 7] = y + pad;
}

// ---------------- host ----------------
template <typename T>
static void run_scan_t(const T* in, T* out, int n, T* blockSums, T* totalOut,
                       hipStream_t stream) {
    int nb = (n + SCAN_TILE - 1) / SCAN_TILE;
    scanA_t<T><<<nb, SCAN_BLOCK, 0, stream>>>(in, out, n, blockSums);
    scanB_t<T><<<1, 256, 0, stream>>>(blockSums, nb, totalOut);
    scanC_t<T><<<nb, SCAN_BLOCK, 0, stream>>>(out, n, blockSums);
}

extern "C" void kernel_launch(void* const* d_in, const int* in_sizes, int n_in,
                              void* d_out, int out_size, void* d_ws, size_t ws_size,
                              hipStream_t stream) {
    const float* pos = (const float*)d_in[0];
    const float* sdf = (const float*)d_in[1];
    const int* tet = (const int*)d_in[2];
    int V = in_sizes[1];
    int T = in_sizes[2] / 4;
    float* out = (float*)d_out;

    char* p = (char*)d_ws;
    auto alloc = [&](size_t bytes) -> void* {
        void* r = (void*)p;
        p += (bytes + 255) & ~(size_t)255;
        return r;
    };
    u8*  ti8         = (u8*) alloc((size_t)T);
    u64* tetPack     = (u64*)alloc((size_t)T * 8);
    u64* tetScan     = (u64*)alloc((size_t)T * 8);
    u32* bucketCnt   = (u32*)alloc((size_t)V * 4);
    u32* padCnt      = (u32*)alloc((size_t)V * 4);
    u32* bucketStart = (u32*)alloc((size_t)V * 4);
    u32* cursor      = (u32*)alloc((size_t)V * 4);
    u32* crossCnt    = (u32*)alloc((size_t)V * 4);
    u32* crossScan   = (u32*)alloc((size_t)V * 4);
    uint2* meta2     = (uint2*)alloc((size_t)V * 8);
    u32* maxArr      = (u32*)alloc(((size_t)6 * T + 16 * (size_t)V) * 4);
    u64* blockSums64 = (u64*)alloc(2048 * 8);
    u32* blockSums32 = (u32*)alloc(2048 * 4);
    u64* meta64      = (u64*)alloc(8 * 8);
    u32* NePtr       = (u32*)(meta64 + 4);

    long long M = (2LL * T + 1) / 2;
    int Ngrid = (int)std::sqrt((double)M);
    while ((long long)Ngrid * Ngrid < M) ++Ngrid;
    if (Ngrid < 1) Ngrid = 1;
    long long uvFloats = 8LL * Ngrid * Ngrid;

    hipMemsetAsync(bucketCnt, 0, (size_t)V * 4, stream);
    hipMemsetAsync(cursor, 0, (size_t)V * 4, stream);

    int gV = (V + 255) / 256;
    int gT = (T + 255) / 256;

    k_classify_count<<<gT, 256, 0, stream>>>(tet, sdf, ti8, tetPack, bucketCnt, T);
    run_scan_t<u64>(tetPack, tetScan, T, blockSums64, meta64, stream);
    k_pad<<<gV, 256, 0, stream>>>(bucketCnt, padCnt, V);
    run_scan_t<u32>(padCnt, bucketStart, V, blockSums32, nullptr, stream);
    k_fill<<<gT, 256, 0, stream>>>(tet, ti8, bucketStart, cursor, maxArr, T);
    k_sortdedup<<<V, 64, 0, stream>>>(bucketCnt, bucketStart, maxArr, crossCnt, V);
    run_scan_t<u32>(crossCnt, crossScan, V, blockSums32, NePtr, stream);
    k_metapack<<<gV, 256, 0, stream>>>(bucketStart, crossCnt, crossScan, meta2, V);
    k_verts<<<V, 64, 0, stream>>>(crossCnt, bucketStart, maxArr, crossScan,
                                  pos, sdf, out, V);
    k_faces<<<gT, 256, 0, stream>>>(tet, ti8, tetScan, meta2, maxArr,
                                    meta64, NePtr, out, T, Ngrid, uvFloats);
    int gUV = (Ngrid * Ngrid + 255) / 256;
    k_uvs<<<gUV, 256, 0, stream>>>(out, meta64, NePtr, Ngrid);
}